// Round 3
// baseline (6237.097 us; speedup 1.0000x reference)
//
#include <hip/hip_runtime.h>
#include <hip/hip_bf16.h>

typedef __attribute__((ext_vector_type(8))) short bf16x8;   // 8 bf16 MFMA A/B frag
typedef __attribute__((ext_vector_type(4))) short bf16x4;   // 4 bf16 (8B)
typedef __attribute__((ext_vector_type(4))) float floatx4;  // MFMA C/D frag / 16B container
typedef __attribute__((ext_vector_type(4))) unsigned u32x4; // 4 flags

#define MFMA_BF16_16x16x32(a, b, c) __builtin_amdgcn_mfma_f32_16x16x32_bf16((a), (b), (c), 0, 0, 0)

#define B_SZ 64
#define T_SZ 512
#define DIN  1024
#define DH   2048
#define DOUT 1024
#define NBLK 64          // persistent grid
#define NTHR 512         // 8 waves/block -> 2 waves/SIMD
#define NW   8
#define KW   (DH / NW)   // 256 K-range per wave
#define COLS 32          // h columns owned per block
#define HELEMS ((size_t)B_SZ * DH)   // bf16 elems per h buffer (m-major [64][2048])

union f4b8 { floatx4 f; bf16x8 b; };
__device__ inline bf16x8 asb(floatx4 f) { f4b8 u; u.f = f; return u.b; }

__device__ inline void st_coh(unsigned* p, unsigned v) {
  __hip_atomic_store(p, v, __ATOMIC_RELAXED, __HIP_MEMORY_SCOPE_AGENT);
}
__device__ inline void st_coh64(unsigned long long* p, unsigned long long v) {
  __hip_atomic_store(p, v, __ATOMIC_RELAXED, __HIP_MEMORY_SCOPE_AGENT);
}

// MALL-direct coherent loads (bypass L1+L2): no cache-wide fences needed.
#define LD128_COH(dst, ptr) \
  asm volatile("global_load_dwordx4 %0, %1, off sc0 sc1" : "=v"(dst) : "v"(ptr))
#define LD128_COHU(dst, ptr) \
  asm volatile("global_load_dwordx4 %0, %1, off sc0 sc1" : "=v"(dst) : "v"(ptr))
// plain cached load (read-only XH stream), asm so vmcnt accounting is exact
#define LD64_PLAIN(dst, ptr) \
  asm volatile("global_load_dwordx2 %0, %1, off" : "=v"(dst) : "v"(ptr))
// Counted wait + scheduler fence (rule #18: keep MFMAs below the waitcnt).
#define WAIT_VM(n) do { \
  asm volatile("s_waitcnt vmcnt(" n ")" ::: "memory"); \
  __builtin_amdgcn_sched_barrier(0); } while (0)

// Issue the 8 A-frag loads for k16 = 2g, 2g+1 (i = 0..3 rows x 2 k-halves).
#define ISSUE_GROUP(Ab, g) do { \
  const __hip_bfloat16* _p0 = hrow + (size_t)(2*(g)) * 32; \
  const __hip_bfloat16* _p1 = hrow + (size_t)(2*(g)+1) * 32; \
  LD128_COH(Ab[0], _p0); \
  LD128_COH(Ab[1], _p0 + (size_t)16*DH); \
  LD128_COH(Ab[2], _p0 + (size_t)32*DH); \
  LD128_COH(Ab[3], _p0 + (size_t)48*DH); \
  LD128_COH(Ab[4], _p1); \
  LD128_COH(Ab[5], _p1 + (size_t)16*DH); \
  LD128_COH(Ab[6], _p1 + (size_t)32*DH); \
  LD128_COH(Ab[7], _p1 + (size_t)48*DH); \
} while (0)

// 16 MFMAs consuming group g (k16 = 2g, 2g+1).
#define MFMA_GROUP(Ab, g) do { \
  _Pragma("unroll") \
  for (int _i = 0; _i < 4; ++_i) { \
    acc[_i][0] = MFMA_BF16_16x16x32(Ab[_i], asb(wreg[0][2*(g)]), acc[_i][0]); \
    acc[_i][1] = MFMA_BF16_16x16x32(Ab[_i], asb(wreg[1][2*(g)]), acc[_i][1]); \
  } \
  _Pragma("unroll") \
  for (int _i = 0; _i < 4; ++_i) { \
    acc[_i][0] = MFMA_BF16_16x16x32(Ab[4+_i], asb(wreg[0][2*(g)+1]), acc[_i][0]); \
    acc[_i][1] = MFMA_BF16_16x16x32(Ab[4+_i], asb(wreg[1][2*(g)+1]), acc[_i][1]); \
  } \
} while (0)

__device__ inline bf16x8 cvt8(float4 a, float4 b) {
  union { bf16x8 v; __hip_bfloat16 h[8]; } u;
  u.h[0] = __float2bfloat16(a.x); u.h[1] = __float2bfloat16(a.y);
  u.h[2] = __float2bfloat16(a.z); u.h[3] = __float2bfloat16(a.w);
  u.h[4] = __float2bfloat16(b.x); u.h[5] = __float2bfloat16(b.y);
  u.h[6] = __float2bfloat16(b.z); u.h[7] = __float2bfloat16(b.w);
  return u.v;
}

// ---------------------------------------------------------------------------
// fp32 -> bf16 quantize (RNE), 8 elems/thread.
// ---------------------------------------------------------------------------
__global__ __launch_bounds__(256) void f32_to_bf16(
    const float* __restrict__ in, __hip_bfloat16* __restrict__ out, long n)
{
  long i = ((long)blockIdx.x * 256 + threadIdx.x) * 8;
  if (i + 8 <= n) {
    float4 a = *(const float4*)(in + i);
    float4 b = *(const float4*)(in + i + 4);
    *(bf16x8*)(out + i) = cvt8(a, b);
  }
}

// ---------------------------------------------------------------------------
// Kernel 1: XH = X @ Wxh^T + bxh  (fp32 in, bf16 out). 128x128 tile, BK=64.
// (unchanged, known-good)
// ---------------------------------------------------------------------------
__global__ __launch_bounds__(256) void xh_gemm(
    const float* __restrict__ X,
    const float* __restrict__ W,
    const float* __restrict__ bias,
    __hip_bfloat16* __restrict__ XH)
{
  const int K = DIN;
  const int N = DH;
  __shared__ __hip_bfloat16 As[128][64];
  __shared__ __hip_bfloat16 Bs[128][64];

  const int nb  = N / 128;
  const int bm  = blockIdx.x / nb;
  const int bn  = blockIdx.x % nb;
  const int m0  = bm * 128, n0 = bn * 128;
  const int tid = threadIdx.x;
  const int lane = tid & 63;
  const int wave = tid >> 6;
  const int wm  = (wave >> 1) * 64;
  const int wn  = (wave & 1) * 64;
  const int col = lane & 15;
  const int quad = lane >> 4;

  const floatx4 Z = {0.f, 0.f, 0.f, 0.f};
  floatx4 acc[4][4];
  #pragma unroll
  for (int i = 0; i < 4; ++i)
    #pragma unroll
    for (int j = 0; j < 4; ++j) acc[i][j] = Z;

  const int srow = tid >> 3;
  const int scol = (tid & 7) * 8;

  for (int k0 = 0; k0 < K; k0 += 64) {
    __syncthreads();
    #pragma unroll
    for (int p = 0; p < 4; ++p) {
      int r = srow + p * 32;
      const float* xs = &X[(long)(m0 + r) * K + k0 + scol];
      const float* wsrc = &W[(long)(n0 + r) * K + k0 + scol];
      *(bf16x8*)(&As[r][scol]) = cvt8(*(const float4*)xs,   *(const float4*)(xs + 4));
      *(bf16x8*)(&Bs[r][scol]) = cvt8(*(const float4*)wsrc, *(const float4*)(wsrc + 4));
    }
    __syncthreads();
    #pragma unroll
    for (int kk = 0; kk < 64; kk += 32) {
      const int kr = kk + quad * 8;
      bf16x8 a[4], b[4];
      #pragma unroll
      for (int i = 0; i < 4; ++i) a[i] = *(const bf16x8*)(&As[wm + i*16 + col][kr]);
      #pragma unroll
      for (int j = 0; j < 4; ++j) b[j] = *(const bf16x8*)(&Bs[wn + j*16 + col][kr]);
      #pragma unroll
      for (int i = 0; i < 4; ++i)
        #pragma unroll
        for (int j = 0; j < 4; ++j)
          acc[i][j] = MFMA_BF16_16x16x32(a[i], b[j], acc[i][j]);
    }
  }

  #pragma unroll
  for (int j = 0; j < 4; ++j) {
    const int n = n0 + wn + j*16 + col;
    const float bv = bias[n];
    #pragma unroll
    for (int i = 0; i < 4; ++i) {
      const int mr = m0 + wm + i*16 + quad*4;
      #pragma unroll
      for (int r = 0; r < 4; ++r)
        XH[(long)(mr + r) * N + n] = __float2bfloat16(acc[i][j][r] + bv);
    }
  }
}

// ---------------------------------------------------------------------------
// Per-wave dataflow gate: spin until this wave's 8 producer flags >= want.
// f0/f1 may hold prefetched values (checked before any reload).
// flag[b] = s  <=>  block b has published h_s (stores drained before flag).
// ---------------------------------------------------------------------------
__device__ inline void spin_flags(const unsigned* fp, unsigned want,
                                  u32x4& f0, u32x4& f1) {
  for (;;) {
    if (f0.x >= want && f0.y >= want && f0.z >= want && f0.w >= want &&
        f1.x >= want && f1.y >= want && f1.z >= want && f1.w >= want) break;
    LD128_COHU(f0, fp);
    LD128_COHU(f1, fp + 4);
    WAIT_VM("0");
  }
}

// ---------------------------------------------------------------------------
// Kernel 2: persistent Elman recurrence + final projection.
//   64 blocks x 512 thr (8 waves). Wave w owns K-slice [w*256, w*256+256) =
//   columns of producer blocks 8w..8w+7 ONLY -> per-wave dataflow flags
//   replace the global grid barrier. Whh slice pinned in regs; h exchanged
//   via MALL-direct b128 loads with counted vmcnt pipelining.
//   Backpressure proof: block writes h_{t+1} only after all its waves saw
//   flags >= t (all 64 blocks published h_t => all finished reading h_{t-1}),
//   so the double buffer can never be overwritten while still being read.
// ---------------------------------------------------------------------------
__global__ __launch_bounds__(NTHR, 2) void elman_persistent(
    const __hip_bfloat16* __restrict__ XH,    // [64][512][2048] bf16
    const __hip_bfloat16* __restrict__ Whh,   // [2048][2048] bf16
    const __hip_bfloat16* __restrict__ Why,   // [1024][2048] bf16
    const float* __restrict__ bhy,            // [1024] fp32
    __hip_bfloat16* __restrict__ hbuf,        // [2][64][2048] bf16, m-major (host-zeroed)
    float* __restrict__ Y,                    // [64][1024] fp32 = d_out
    unsigned* __restrict__ flags)             // [64] u32, contiguous (host-zeroed)
{
  __shared__ __align__(16) float partial[NW][B_SZ][COLS + 4];  // [8][64][36]
  const int tid  = threadIdx.x;
  const int lane = tid & 63;
  const int wave = tid >> 6;        // 0..7
  const int bid  = blockIdx.x;
  const int n0   = bid * COLS;
  const int col  = lane & 15;
  const int quad = lane >> 4;
  const int kw   = wave * KW;       // this wave's K base

  const int mrow = tid >> 3;        // reduce/store: batch row (0..63)
  const int grp  = tid & 7;         // 8 col-groups of 4
  const int mcol = grp * 4;

  const unsigned* flagp = flags + wave * 8;   // this wave's 8 producers

  // Pin Whh B-frags (asm anti-remat). 2 n-frags x 8 k16 x 16B = 64 VGPR.
  floatx4 wreg[2][8];
  #pragma unroll
  for (int nf = 0; nf < 2; ++nf) {
    const __hip_bfloat16* wrow = Whh + (long)(n0 + nf*16 + col) * DH + kw + quad * 8;
    #pragma unroll
    for (int k16 = 0; k16 < 8; ++k16) {
      wreg[nf][k16] = *(const floatx4*)(wrow + k16 * 32);
      asm volatile("" : "+v"(wreg[nf][k16]));
    }
  }

  // h_0 = 0 comes from host-side memset of hbuf; flags memset to 0 = "h_0
  // published". No init barrier needed (spin want=0 passes trivially).

  // XH stream t=0 (plain cached load; compiler-waited before first use)
  const __hip_bfloat16* xptr = XH + (size_t)mrow * T_SZ * DH + n0 + mcol;
  bf16x4 xv = *(const bf16x4*)xptr;

  int cur = 0;
  const floatx4 Z = {0.f, 0.f, 0.f, 0.f};
  u32x4 f0 = {0, 0, 0, 0}, f1 = {0, 0, 0, 0};   // passes the t=0 spin

  for (int t = 0; t < T_SZ; ++t) {
    // wait for THIS wave's 8 producers to publish h_t (prefetched flags first)
    spin_flags(flagp, (unsigned)t, f0, f1);

    // prefetch next xh inside the counted window (asm so the count is exact)
    bf16x4 xvn;
    {
      const __hip_bfloat16* xp = xptr + (size_t)(t + 1 < T_SZ ? t + 1 : t) * DH;
      LD64_PLAIN(xvn, xp);
    }
    const __hip_bfloat16* hrow = hbuf + (size_t)cur * HELEMS + kw + quad * 8
                               + (size_t)col * DH;
    floatx4 acc[4][2];
    #pragma unroll
    for (int i = 0; i < 4; ++i) { acc[i][0] = Z; acc[i][1] = Z; }

    bf16x8 A0[8], A1[8];
    // Counted-vmcnt pipeline. Outstanding audit (xvn issued first):
    //   issue xvn+G0 (9), G1 (17) -> wait(8) retires xvn+G0
    //   issue G2 (16)             -> wait(8) retires G1
    //   issue G3 (16)             -> wait(8) retires G2
    //                                wait(0) retires G3
    ISSUE_GROUP(A0, 0);
    ISSUE_GROUP(A1, 1);
    WAIT_VM("8");
    MFMA_GROUP(A0, 0);
    ISSUE_GROUP(A0, 2);
    WAIT_VM("8");
    MFMA_GROUP(A1, 1);
    ISSUE_GROUP(A1, 3);
    WAIT_VM("8");
    MFMA_GROUP(A0, 2);
    WAIT_VM("0");
    MFMA_GROUP(A1, 3);

    // partials to LDS (C/D: m = i*16+quad*4+r, n = nf*16+col)
    #pragma unroll
    for (int i = 0; i < 4; ++i)
      #pragma unroll
      for (int nf = 0; nf < 2; ++nf)
        #pragma unroll
        for (int r = 0; r < 4; ++r)
          partial[wave][i*16 + quad*4 + r][nf*16 + col] = acc[i][nf][r];
    __syncthreads();
    // reduce 8 waves, + xh_t, relu, pack 4 n-cols, write-through u64 store
    {
      floatx4 s = Z;
      #pragma unroll
      for (int w = 0; w < NW; ++w)
        s += *(const floatx4*)(&partial[w][mrow][mcol]);
      union { bf16x4 v; __hip_bfloat16 hh[4]; unsigned long long q; } o, xu;
      xu.v = xv;
      #pragma unroll
      for (int c = 0; c < 4; ++c) {
        float v = s[c] + __bfloat162float(xu.hh[c]);
        v = v > 0.f ? v : 0.f;
        o.hh[c] = __float2bfloat16(v);
      }
      st_coh64((unsigned long long*)(hbuf + (size_t)(1 - cur) * HELEMS
                                     + (size_t)mrow * DH + n0 + mcol), o.q);
    }
    // prefetch next spin's flags inside the same drain window, then drain:
    // all h stores + flag loads acked at MALL before the barrier.
    LD128_COHU(f0, flagp);
    LD128_COHU(f1, flagp + 4);
    asm volatile("s_waitcnt vmcnt(0)" ::: "memory");
    __syncthreads();   // all waves drained + all partial reads done (LDS reuse)
    if (tid == 0)
      st_coh(flags + bid, (unsigned)(t + 1));   // publish h_{t+1}
    cur ^= 1;
    xv = xvn;
  }

  // Final projection: y = h_final @ Why^T + bhy  (blocks 0..31, fp32 out).
  // h_512 lives in hbuf[0] (cur back to 0). Gate on flags >= 512.
  if (n0 < DOUT) {
    spin_flags(flagp, (unsigned)T_SZ, f0, f1);
    const __hip_bfloat16* hrow = hbuf + (size_t)cur * HELEMS + kw + quad * 8
                               + (size_t)col * DH;
    floatx4 acc[4][2];
    #pragma unroll
    for (int i = 0; i < 4; ++i) { acc[i][0] = Z; acc[i][1] = Z; }
    bf16x8 A0[8];
    #pragma unroll
    for (int g = 0; g < 4; ++g) {
      ISSUE_GROUP(A0, g);
      WAIT_VM("0");
      #pragma unroll
      for (int kk = 0; kk < 2; ++kk) {
        const int k16 = 2*g + kk;
        bf16x8 b0 = *(const bf16x8*)(Why + (long)(n0 +      col) * DH + kw + k16*32 + quad*8);
        bf16x8 b1 = *(const bf16x8*)(Why + (long)(n0 + 16 + col) * DH + kw + k16*32 + quad*8);
        #pragma unroll
        for (int i = 0; i < 4; ++i) {
          acc[i][0] = MFMA_BF16_16x16x32(A0[4*kk + i], b0, acc[i][0]);
          acc[i][1] = MFMA_BF16_16x16x32(A0[4*kk + i], b1, acc[i][1]);
        }
      }
    }
    #pragma unroll
    for (int i = 0; i < 4; ++i)
      #pragma unroll
      for (int nf = 0; nf < 2; ++nf)
        #pragma unroll
        for (int r = 0; r < 4; ++r)
          partial[wave][i*16 + quad*4 + r][nf*16 + col] = acc[i][nf][r];
    __syncthreads();
    {
      floatx4 s = Z;
      #pragma unroll
      for (int w = 0; w < NW; ++w)
        s += *(const floatx4*)(&partial[w][mrow][mcol]);
      float4 bv = *(const float4*)(&bhy[n0 + mcol]);
      float4 out;
      out.x = s[0] + bv.x; out.y = s[1] + bv.y;
      out.z = s[2] + bv.z; out.w = s[3] + bv.w;
      *(float4*)(&Y[(size_t)mrow * DOUT + n0 + mcol]) = out;
    }
  }
}

// ---------------------------------------------------------------------------
extern "C" void kernel_launch(void* const* d_in, const int* in_sizes, int n_in,
                              void* d_out, int out_size, void* d_ws, size_t ws_size,
                              hipStream_t stream) {
  const float* x   = (const float*)d_in[0];
  const float* Wxh = (const float*)d_in[1];
  const float* bxh = (const float*)d_in[2];
  const float* Whh = (const float*)d_in[3];
  const float* Why = (const float*)d_in[4];
  const float* bhy = (const float*)d_in[5];
  float* y = (float*)d_out;

  char* ws = (char*)d_ws;
  const size_t XH_BYTES  = (size_t)B_SZ * T_SZ * DH * 2;   // 128 MiB
  const size_t WHH_BYTES = (size_t)DH * DH * 2;            // 8 MiB
  const size_t WHY_BYTES = (size_t)DOUT * DH * 2;          // 4 MiB
  const size_t H_BYTES   = (size_t)2 * HELEMS * 2;         // 512 KiB
  const size_t FLAG_BYTES = 64 * 4;                        // 64 contiguous u32
  __hip_bfloat16* XH     = (__hip_bfloat16*)ws;
  __hip_bfloat16* Whh_bf = (__hip_bfloat16*)(ws + XH_BYTES);
  __hip_bfloat16* Why_bf = (__hip_bfloat16*)(ws + XH_BYTES + WHH_BYTES);
  __hip_bfloat16* hbuf   = (__hip_bfloat16*)(ws + XH_BYTES + WHH_BYTES + WHY_BYTES);
  unsigned* flags        = (unsigned*)(ws + XH_BYTES + WHH_BYTES + WHY_BYTES + H_BYTES);

  hipMemsetAsync(hbuf, 0, H_BYTES, stream);      // h_0 = 0 (+ buffer 1 cleared)
  hipMemsetAsync(flags, 0, FLAG_BYTES, stream);  // flag[b] = 0 = "h_0 published"
  f32_to_bf16<<<dim3((DH*DH)/(256*8)),   dim3(256), 0, stream>>>(Whh, Whh_bf, (long)DH*DH);
  f32_to_bf16<<<dim3((DOUT*DH)/(256*8)), dim3(256), 0, stream>>>(Why, Why_bf, (long)DOUT*DH);
  xh_gemm<<<dim3((32768/128) * (DH/128)), dim3(256), 0, stream>>>(x, Wxh, bxh, XH);
  elman_persistent<<<dim3(NBLK), dim3(NTHR), 0, stream>>>(
      XH, Whh_bf, Why_bf, bhy, hbuf, y, flags);
}

// Round 5
// 5304.582 us; speedup vs baseline: 1.1758x; 1.1758x over previous
//
#include <hip/hip_runtime.h>
#include <hip/hip_bf16.h>

typedef __attribute__((ext_vector_type(8))) short bf16x8;   // 8 bf16 MFMA A/B frag
typedef __attribute__((ext_vector_type(4))) short bf16x4;   // 4 bf16 (8B)
typedef __attribute__((ext_vector_type(4))) float floatx4;  // MFMA C/D frag / 16B container

#define MFMA_BF16_16x16x32(a, b, c) __builtin_amdgcn_mfma_f32_16x16x32_bf16((a), (b), (c), 0, 0, 0)

#define B_SZ 64
#define T_SZ 512
#define DIN  1024
#define DH   2048
#define DOUT 1024
#define NBLK 64          // persistent grid
#define NTHR 512         // 8 waves/block -> 2 waves/SIMD
#define NW   8
#define KW   (DH / NW)   // 256 K-range per wave
#define COLS 32          // h columns owned per block
#define HELEMS ((size_t)B_SZ * DH)   // bf16 elems per h buffer (m-major [64][2048])

union f4b8 { floatx4 f; bf16x8 b; };
__device__ inline bf16x8 asb(floatx4 f) { f4b8 u; u.f = f; return u.b; }
union b8u4 { bf16x8 b; unsigned d[4]; };

__device__ inline void st_coh64(unsigned long long* p, unsigned long long v) {
  __hip_atomic_store(p, v, __ATOMIC_RELAXED, __HIP_MEMORY_SCOPE_AGENT);
}

// MALL-direct coherent loads (bypass L1+L2): no cache-wide fences needed.
#define LD128_COH(dst, ptr) \
  asm volatile("global_load_dwordx4 %0, %1, off sc0 sc1" : "=v"(dst) : "v"(ptr))
// plain cached load (read-only XH stream), asm so vmcnt accounting is exact
#define LD64_PLAIN(dst, ptr) \
  asm volatile("global_load_dwordx2 %0, %1, off" : "=v"(dst) : "v"(ptr))
// Counted wait + scheduler fence (rule #18: keep reg-only verify/MFMA below).
#define WAIT_VM(n) do { \
  asm volatile("s_waitcnt vmcnt(" n ")" ::: "memory"); \
  __builtin_amdgcn_sched_barrier(0); } while (0)

// Issue the 8 A-frag loads for k16 = 2g, 2g+1 (i = 0..3 rows x 2 k-halves).
#define ISSUE_GROUP(Ab, g) do { \
  const __hip_bfloat16* _p0 = hrow + (size_t)(2*(g)) * 32; \
  const __hip_bfloat16* _p1 = hrow + (size_t)(2*(g)+1) * 32; \
  LD128_COH(Ab[0], _p0); \
  LD128_COH(Ab[1], _p0 + (size_t)16*DH); \
  LD128_COH(Ab[2], _p0 + (size_t)32*DH); \
  LD128_COH(Ab[3], _p0 + (size_t)48*DH); \
  LD128_COH(Ab[4], _p1); \
  LD128_COH(Ab[5], _p1 + (size_t)16*DH); \
  LD128_COH(Ab[6], _p1 + (size_t)32*DH); \
  LD128_COH(Ab[7], _p1 + (size_t)48*DH); \
} while (0)

// Tag verify: sign bits of all 32 dwords must equal mexp (0 or 0x80008000).
__device__ inline unsigned grp_mismatch(const bf16x8* Ab, unsigned mexp) {
  unsigned acc = 0u;
  #pragma unroll
  for (int j = 0; j < 8; ++j) {
    b8u4 u; u.b = Ab[j];
    acc |= (u.d[0] ^ mexp) | (u.d[1] ^ mexp) | (u.d[2] ^ mexp) | (u.d[3] ^ mexp);
  }
  return acc & 0x80008000u;
}
// Retry-until-fresh: data IS the flag. s_sleep paces retries (~64 cy) so
// spinning waves don't flood the MALL while producers finish.
#define ACQUIRE(Ab, g, mexp) \
  while (!__all(grp_mismatch((Ab), (mexp)) == 0u)) { \
    __builtin_amdgcn_s_sleep(1); \
    ISSUE_GROUP(Ab, g); WAIT_VM("0"); }

__device__ inline void clean_grp(bf16x8* Ab) {   // strip tag-1 sign bits
  #pragma unroll
  for (int j = 0; j < 8; ++j) {
    b8u4 u; u.b = Ab[j];
    u.d[0] &= 0x7fff7fffu; u.d[1] &= 0x7fff7fffu;
    u.d[2] &= 0x7fff7fffu; u.d[3] &= 0x7fff7fffu;
    Ab[j] = u.b;
  }
}

// 16 MFMAs consuming group g (k16 = 2g, 2g+1).
#define MFMA_GROUP(Ab, g) do { \
  _Pragma("unroll") \
  for (int _i = 0; _i < 4; ++_i) { \
    acc[_i][0] = MFMA_BF16_16x16x32(Ab[_i], asb(wreg[0][2*(g)]), acc[_i][0]); \
    acc[_i][1] = MFMA_BF16_16x16x32(Ab[_i], asb(wreg[1][2*(g)]), acc[_i][1]); \
  } \
  _Pragma("unroll") \
  for (int _i = 0; _i < 4; ++_i) { \
    acc[_i][0] = MFMA_BF16_16x16x32(Ab[4+_i], asb(wreg[0][2*(g)+1]), acc[_i][0]); \
    acc[_i][1] = MFMA_BF16_16x16x32(Ab[4+_i], asb(wreg[1][2*(g)+1]), acc[_i][1]); \
  } \
} while (0)

__device__ inline bf16x8 cvt8(float4 a, float4 b) {
  union { bf16x8 v; __hip_bfloat16 h[8]; } u;
  u.h[0] = __float2bfloat16(a.x); u.h[1] = __float2bfloat16(a.y);
  u.h[2] = __float2bfloat16(a.z); u.h[3] = __float2bfloat16(a.w);
  u.h[4] = __float2bfloat16(b.x); u.h[5] = __float2bfloat16(b.y);
  u.h[6] = __float2bfloat16(b.z); u.h[7] = __float2bfloat16(b.w);
  return u.v;
}

// ---------------------------------------------------------------------------
// fp32 -> bf16 quantize (RNE), 8 elems/thread.
// ---------------------------------------------------------------------------
__global__ __launch_bounds__(256) void f32_to_bf16(
    const float* __restrict__ in, __hip_bfloat16* __restrict__ out, long n)
{
  long i = ((long)blockIdx.x * 256 + threadIdx.x) * 8;
  if (i + 8 <= n) {
    float4 a = *(const float4*)(in + i);
    float4 b = *(const float4*)(in + i + 4);
    *(bf16x8*)(out + i) = cvt8(a, b);
  }
}

// ---------------------------------------------------------------------------
// Kernel 1: XH = X @ Wxh^T + bxh  (fp32 in, bf16 out). 128x128 tile, BK=64.
// (unchanged, known-good)
// ---------------------------------------------------------------------------
__global__ __launch_bounds__(256) void xh_gemm(
    const float* __restrict__ X,
    const float* __restrict__ W,
    const float* __restrict__ bias,
    __hip_bfloat16* __restrict__ XH)
{
  const int K = DIN;
  const int N = DH;
  __shared__ __hip_bfloat16 As[128][64];
  __shared__ __hip_bfloat16 Bs[128][64];

  const int nb  = N / 128;
  const int bm  = blockIdx.x / nb;
  const int bn  = blockIdx.x % nb;
  const int m0  = bm * 128, n0 = bn * 128;
  const int tid = threadIdx.x;
  const int lane = tid & 63;
  const int wave = tid >> 6;
  const int wm  = (wave >> 1) * 64;
  const int wn  = (wave & 1) * 64;
  const int col = lane & 15;
  const int quad = lane >> 4;

  const floatx4 Z = {0.f, 0.f, 0.f, 0.f};
  floatx4 acc[4][4];
  #pragma unroll
  for (int i = 0; i < 4; ++i)
    #pragma unroll
    for (int j = 0; j < 4; ++j) acc[i][j] = Z;

  const int srow = tid >> 3;
  const int scol = (tid & 7) * 8;

  for (int k0 = 0; k0 < K; k0 += 64) {
    __syncthreads();
    #pragma unroll
    for (int p = 0; p < 4; ++p) {
      int r = srow + p * 32;
      const float* xs = &X[(long)(m0 + r) * K + k0 + scol];
      const float* wsrc = &W[(long)(n0 + r) * K + k0 + scol];
      *(bf16x8*)(&As[r][scol]) = cvt8(*(const float4*)xs,   *(const float4*)(xs + 4));
      *(bf16x8*)(&Bs[r][scol]) = cvt8(*(const float4*)wsrc, *(const float4*)(wsrc + 4));
    }
    __syncthreads();
    #pragma unroll
    for (int kk = 0; kk < 64; kk += 32) {
      const int kr = kk + quad * 8;
      bf16x8 a[4], b[4];
      #pragma unroll
      for (int i = 0; i < 4; ++i) a[i] = *(const bf16x8*)(&As[wm + i*16 + col][kr]);
      #pragma unroll
      for (int j = 0; j < 4; ++j) b[j] = *(const bf16x8*)(&Bs[wn + j*16 + col][kr]);
      #pragma unroll
      for (int i = 0; i < 4; ++i)
        #pragma unroll
        for (int j = 0; j < 4; ++j)
          acc[i][j] = MFMA_BF16_16x16x32(a[i], b[j], acc[i][j]);
    }
  }

  #pragma unroll
  for (int j = 0; j < 4; ++j) {
    const int n = n0 + wn + j*16 + col;
    const float bv = bias[n];
    #pragma unroll
    for (int i = 0; i < 4; ++i) {
      const int mr = m0 + wm + i*16 + quad*4;
      #pragma unroll
      for (int r = 0; r < 4; ++r)
        XH[(long)(mr + r) * N + n] = __float2bfloat16(acc[i][j][r] + bv);
    }
  }
}

// ---------------------------------------------------------------------------
// Kernel 2: persistent Elman recurrence + final projection.
//   SYNC-FREE dataflow: h values carry a 1-bit step tag in their sign bits
//   (legal: post-ReLU h >= 0). tag(t) = (t>>1)&1 alternates between
//   consecutive uses of each double buffer. Consumers load speculatively,
//   verify tags in-register, retry stale groups. No grid barrier, no flags,
//   no store-drain on the critical path.
//   Inter-block safety: a block stores h_{t+1} only after verifying ALL of
//   h_t, so global skew <= 1 step -> double-buffer overwrite safe, no ABA.
//   Intra-block safety (R4's bug, fixed): TWO intra-block barriers per step.
//   Barrier 1 (__syncthreads): partial[] writes visible before reduce reads.
//   Barrier 2 (raw s_barrier, NO vmcnt drain): reduce reads of step t done
//   before any wave's step-t+1 partial writes. Raw form avoids the compiler's
//   vmcnt(0) drain -- the h-store ack stays off the critical path; LDS read
//   ordering is already enforced because reduce values are consumed before
//   the store is computed.
// ---------------------------------------------------------------------------
__global__ __launch_bounds__(NTHR, 2) void elman_persistent(
    const __hip_bfloat16* __restrict__ XH,    // [64][512][2048] bf16
    const __hip_bfloat16* __restrict__ Whh,   // [2048][2048] bf16
    const __hip_bfloat16* __restrict__ Why,   // [1024][2048] bf16
    const float* __restrict__ bhy,            // [1024] fp32
    __hip_bfloat16* __restrict__ hbuf,        // [2][64][2048] bf16 (buf0=0x00, buf1=0x80)
    float* __restrict__ Y)                    // [64][1024] fp32 = d_out
{
  __shared__ __align__(16) float partial[NW][B_SZ][COLS + 4];  // [8][64][36]
  const int tid  = threadIdx.x;
  const int lane = tid & 63;
  const int wave = tid >> 6;        // 0..7
  const int bid  = blockIdx.x;
  const int n0   = bid * COLS;
  const int col  = lane & 15;
  const int quad = lane >> 4;
  const int kw   = wave * KW;       // this wave's K base

  const int mrow = tid >> 3;        // reduce/store: batch row (0..63)
  const int grp  = tid & 7;         // 8 col-groups of 4
  const int mcol = grp * 4;

  // Pin Whh B-frags (asm anti-remat). 2 n-frags x 8 k16 x 16B = 64 VGPR.
  floatx4 wreg[2][8];
  #pragma unroll
  for (int nf = 0; nf < 2; ++nf) {
    const __hip_bfloat16* wrow = Whh + (long)(n0 + nf*16 + col) * DH + kw + quad * 8;
    #pragma unroll
    for (int k16 = 0; k16 < 8; ++k16) {
      wreg[nf][k16] = *(const floatx4*)(wrow + k16 * 32);
      asm volatile("" : "+v"(wreg[nf][k16]));
    }
  }

  // h_0 = +0.0 (tag 0) from host memset of buf0; buf1 pre-filled with 0x80
  // bytes = stale-tag pattern, so step-1 consumers can't pass on init data.

  // XH stream t=0 (asm load so it joins our vmcnt accounting; retires at
  // the first counted wait).
  const __hip_bfloat16* xptr = XH + (size_t)mrow * T_SZ * DH + n0 + mcol;
  bf16x4 xv;
  LD64_PLAIN(xv, xptr);

  const floatx4 Z = {0.f, 0.f, 0.f, 0.f};

  for (int t = 0; t < T_SZ; ++t) {
    const unsigned mexp = ((t >> 1) & 1) ? 0x80008000u : 0u;           // expected tag of h_t
    const unsigned long long smask =
        (((t + 1) >> 1) & 1) ? 0x8000800080008000ull : 0ull;           // tag of h_{t+1}

    // prefetch next xh inside the counted window (asm: count exact)
    bf16x4 xvn;
    {
      const __hip_bfloat16* xp = xptr + (size_t)(t + 1 < T_SZ ? t + 1 : t) * DH;
      LD64_PLAIN(xvn, xp);
    }
    const __hip_bfloat16* hrow = hbuf + (size_t)(t & 1) * HELEMS + kw + quad * 8
                               + (size_t)col * DH;
    floatx4 acc[4][2];
    #pragma unroll
    for (int i = 0; i < 4; ++i) { acc[i][0] = Z; acc[i][1] = Z; }

    bf16x8 A0[8], A1[8];
    // Counted-vmcnt pipeline with tag verify. Outstanding audit (prev-iter
    // h-store or initial xv = 1 slot; vmcnt retires in issue order):
    //   [1] + xvn + G0 + G1 = 18 -> WAIT(8) retires slot+xvn+G0
    //   issue G2 (16 or 8 post-retry) -> WAIT(8) retires G1
    //   issue G3                      -> WAIT(8) retires G2
    //                                    WAIT(0) retires G3
    // ACQUIRE re-issues a stale group + WAIT(0); later counted waits then
    // pass immediately (vmcnt <= N), and later ACQUIREs re-verify.
    ISSUE_GROUP(A0, 0);
    ISSUE_GROUP(A1, 1);
    WAIT_VM("8");
    ACQUIRE(A0, 0, mexp);
    if (mexp) clean_grp(A0);
    MFMA_GROUP(A0, 0);
    ISSUE_GROUP(A0, 2);
    WAIT_VM("8");
    ACQUIRE(A1, 1, mexp);
    if (mexp) clean_grp(A1);
    MFMA_GROUP(A1, 1);
    ISSUE_GROUP(A1, 3);
    WAIT_VM("8");
    ACQUIRE(A0, 2, mexp);
    if (mexp) clean_grp(A0);
    MFMA_GROUP(A0, 2);
    WAIT_VM("0");
    ACQUIRE(A1, 3, mexp);
    if (mexp) clean_grp(A1);
    MFMA_GROUP(A1, 3);

    // partials to LDS (C/D: m = i*16+quad*4+r, n = nf*16+col)
    #pragma unroll
    for (int i = 0; i < 4; ++i)
      #pragma unroll
      for (int nf = 0; nf < 2; ++nf)
        #pragma unroll
        for (int r = 0; r < 4; ++r)
          partial[wave][i*16 + quad*4 + r][nf*16 + col] = acc[i][nf][r];
    __syncthreads();   // barrier 1: partial writes -> reduce reads (vmcnt=0 here)
    // reduce 8 waves, + xh_t, relu, tag signs, write-through u64 store.
    // NO vmcnt drain: the consumers' ACQUIRE verifies landing.
    {
      floatx4 s = Z;
      #pragma unroll
      for (int w = 0; w < NW; ++w)
        s += *(const floatx4*)(&partial[w][mrow][mcol]);
      union { bf16x4 v; __hip_bfloat16 hh[4]; unsigned long long q; } o, xu;
      xu.v = xv;
      #pragma unroll
      for (int c = 0; c < 4; ++c) {
        float v = s[c] + __bfloat162float(xu.hh[c]);
        v = v > 0.f ? v : 0.f;
        o.hh[c] = __float2bfloat16(v);
      }
      o.q |= smask;   // stamp step tag into sign bits (values >= 0)
      st_coh64((unsigned long long*)(hbuf + (size_t)((t + 1) & 1) * HELEMS
                                     + (size_t)mrow * DH + n0 + mcol), o.q);
    }
    // barrier 2 (raw, no vmcnt drain): step-t reduce reads complete before
    // any wave's step-t+1 partial writes. This was R4's missing barrier.
    asm volatile("s_waitcnt lgkmcnt(0)" ::: "memory");
    __builtin_amdgcn_s_barrier();
    __builtin_amdgcn_sched_barrier(0);
    xv = xvn;
  }

  // Final projection: y = h_final @ Why^T + bhy  (blocks 0..31, fp32 out).
  // h_512 is in buf0 with tag (512>>1)&1 = 0.
  if (n0 < DOUT) {
    const unsigned mexp = 0u;
    const __hip_bfloat16* hrow = hbuf + kw + quad * 8 + (size_t)col * DH;
    floatx4 acc[4][2];
    #pragma unroll
    for (int i = 0; i < 4; ++i) { acc[i][0] = Z; acc[i][1] = Z; }
    bf16x8 A0[8];
    #pragma unroll
    for (int g = 0; g < 4; ++g) {
      ISSUE_GROUP(A0, g);
      WAIT_VM("0");
      ACQUIRE(A0, g, mexp);
      #pragma unroll
      for (int kk = 0; kk < 2; ++kk) {
        const int k16 = 2*g + kk;
        bf16x8 b0 = *(const bf16x8*)(Why + (long)(n0 +      col) * DH + kw + k16*32 + quad*8);
        bf16x8 b1 = *(const bf16x8*)(Why + (long)(n0 + 16 + col) * DH + kw + k16*32 + quad*8);
        #pragma unroll
        for (int i = 0; i < 4; ++i) {
          acc[i][0] = MFMA_BF16_16x16x32(A0[4*kk + i], b0, acc[i][0]);
          acc[i][1] = MFMA_BF16_16x16x32(A0[4*kk + i], b1, acc[i][1]);
        }
      }
    }
    #pragma unroll
    for (int i = 0; i < 4; ++i)
      #pragma unroll
      for (int nf = 0; nf < 2; ++nf)
        #pragma unroll
        for (int r = 0; r < 4; ++r)
          partial[wave][i*16 + quad*4 + r][nf*16 + col] = acc[i][nf][r];
    __syncthreads();
    {
      floatx4 s = Z;
      #pragma unroll
      for (int w = 0; w < NW; ++w)
        s += *(const floatx4*)(&partial[w][mrow][mcol]);
      float4 bv = *(const float4*)(&bhy[n0 + mcol]);
      float4 out;
      out.x = s[0] + bv.x; out.y = s[1] + bv.y;
      out.z = s[2] + bv.z; out.w = s[3] + bv.w;
      *(float4*)(&Y[(size_t)mrow * DOUT + n0 + mcol]) = out;
    }
  }
}

// ---------------------------------------------------------------------------
extern "C" void kernel_launch(void* const* d_in, const int* in_sizes, int n_in,
                              void* d_out, int out_size, void* d_ws, size_t ws_size,
                              hipStream_t stream) {
  const float* x   = (const float*)d_in[0];
  const float* Wxh = (const float*)d_in[1];
  const float* bxh = (const float*)d_in[2];
  const float* Whh = (const float*)d_in[3];
  const float* Why = (const float*)d_in[4];
  const float* bhy = (const float*)d_in[5];
  float* y = (float*)d_out;

  char* ws = (char*)d_ws;
  const size_t XH_BYTES  = (size_t)B_SZ * T_SZ * DH * 2;   // 128 MiB
  const size_t WHH_BYTES = (size_t)DH * DH * 2;            // 8 MiB
  const size_t WHY_BYTES = (size_t)DOUT * DH * 2;          // 4 MiB
  const size_t HB        = (size_t)HELEMS * 2;             // 256 KiB per buffer
  __hip_bfloat16* XH     = (__hip_bfloat16*)ws;
  __hip_bfloat16* Whh_bf = (__hip_bfloat16*)(ws + XH_BYTES);
  __hip_bfloat16* Why_bf = (__hip_bfloat16*)(ws + XH_BYTES + WHH_BYTES);
  __hip_bfloat16* hbuf   = (__hip_bfloat16*)(ws + XH_BYTES + WHH_BYTES + WHY_BYTES);

  hipMemsetAsync(hbuf, 0x00, HB, stream);                  // buf0 = h_0 = +0, tag 0
  hipMemsetAsync((char*)hbuf + HB, 0x80, HB, stream);      // buf1 = stale-tag pattern
  f32_to_bf16<<<dim3((DH*DH)/(256*8)),   dim3(256), 0, stream>>>(Whh, Whh_bf, (long)DH*DH);
  f32_to_bf16<<<dim3((DOUT*DH)/(256*8)), dim3(256), 0, stream>>>(Why, Why_bf, (long)DOUT*DH);
  xh_gemm<<<dim3((32768/128) * (DH/128)), dim3(256), 0, stream>>>(x, Wxh, bxh, XH);
  elman_persistent<<<dim3(NBLK), dim3(NTHR), 0, stream>>>(
      XH, Whh_bf, Why_bf, bhy, hbuf, y);
}

// Round 7
// 5263.758 us; speedup vs baseline: 1.1849x; 1.0078x over previous
//
#include <hip/hip_runtime.h>
#include <hip/hip_bf16.h>

typedef __attribute__((ext_vector_type(8))) short bf16x8;   // 8 bf16 MFMA A/B frag
typedef __attribute__((ext_vector_type(4))) short bf16x4;   // 4 bf16 (8B)
typedef __attribute__((ext_vector_type(4))) float floatx4;  // MFMA C/D frag / 16B container

#define MFMA_BF16_16x16x32(a, b, c) __builtin_amdgcn_mfma_f32_16x16x32_bf16((a), (b), (c), 0, 0, 0)

#define B_SZ 64
#define T_SZ 512
#define DIN  1024
#define DH   2048
#define DOUT 1024
#define NBLK 64          // persistent grid
#define NTHR 512         // 8 waves/block -> 2 waves/SIMD
#define NW   8
#define KW   (DH / NW)   // 256 K-range per wave
#define COLS 32          // h columns owned per block
#define HELEMS ((size_t)B_SZ * DH)   // bf16 elems per h buffer (m-major [64][2048])

union f4b8 { floatx4 f; bf16x8 b; };
__device__ inline bf16x8 asb(floatx4 f) { f4b8 u; u.f = f; return u.b; }
union b8u4 { bf16x8 b; unsigned d[4]; };

__device__ inline void st_coh64(unsigned long long* p, unsigned long long v) {
  __hip_atomic_store(p, v, __ATOMIC_RELAXED, __HIP_MEMORY_SCOPE_AGENT);
}

// MALL-direct coherent loads (bypass L1+L2): no cache-wide fences needed.
#define LD128_COH(dst, ptr) \
  asm volatile("global_load_dwordx4 %0, %1, off sc0 sc1" : "=v"(dst) : "v"(ptr))
#define LD32_COH(dst, ptr) \
  asm volatile("global_load_dword %0, %1, off sc0 sc1" : "=v"(dst) : "v"(ptr))
// plain cached load (read-only XH stream), asm so vmcnt accounting is exact
#define LD64_PLAIN(dst, ptr) \
  asm volatile("global_load_dwordx2 %0, %1, off" : "=v"(dst) : "v"(ptr))
// Counted wait + scheduler fence (rule #18: keep reg-only verify/MFMA below).
#define WAIT_VM(n) do { \
  asm volatile("s_waitcnt vmcnt(" n ")" ::: "memory"); \
  __builtin_amdgcn_sched_barrier(0); } while (0)

// Issue the 8 A-frag loads for k16 = 2g, 2g+1 from base pointer hb.
#define ISSUE_GROUP(Ab, g, hb) do { \
  const __hip_bfloat16* _p0 = (hb) + (size_t)(2*(g)) * 32; \
  const __hip_bfloat16* _p1 = (hb) + (size_t)(2*(g)+1) * 32; \
  LD128_COH(Ab[0], _p0); \
  LD128_COH(Ab[1], _p0 + (size_t)16*DH); \
  LD128_COH(Ab[2], _p0 + (size_t)32*DH); \
  LD128_COH(Ab[3], _p0 + (size_t)48*DH); \
  LD128_COH(Ab[4], _p1); \
  LD128_COH(Ab[5], _p1 + (size_t)16*DH); \
  LD128_COH(Ab[6], _p1 + (size_t)32*DH); \
  LD128_COH(Ab[7], _p1 + (size_t)48*DH); \
} while (0)

// Tag verify: sign bits of all 32 dwords must equal mexp (0 or 0x80008000).
__device__ inline unsigned grp_mismatch(const bf16x8* Ab, unsigned mexp) {
  unsigned acc = 0u;
  #pragma unroll
  for (int j = 0; j < 8; ++j) {
    b8u4 u; u.b = Ab[j];
    acc |= (u.d[0] ^ mexp) | (u.d[1] ^ mexp) | (u.d[2] ^ mexp) | (u.d[3] ^ mexp);
  }
  return acc & 0x80008000u;
}
// Backstop retry (rare: probe already confirmed freshness; catches the case
// where the probed element landed but a sibling store of the same producer
// hadn't). Each retry = one full RT, s_sleep-paced.
#define ACQUIRE(Ab, g, mexp, hb) \
  while (!__all(grp_mismatch((Ab), (mexp)) == 0u)) { \
    __builtin_amdgcn_s_sleep(1); \
    ISSUE_GROUP(Ab, g, hb); WAIT_VM("0"); }

__device__ inline void clean_grp(bf16x8* Ab) {   // strip tag-1 sign bits
  #pragma unroll
  for (int j = 0; j < 8; ++j) {
    b8u4 u; u.b = Ab[j];
    u.d[0] &= 0x7fff7fffu; u.d[1] &= 0x7fff7fffu;
    u.d[2] &= 0x7fff7fffu; u.d[3] &= 0x7fff7fffu;
    Ab[j] = u.b;
  }
}

// 16 MFMAs consuming group g (k16 = 2g, 2g+1).
#define MFMA_GROUP(Ab, g) do { \
  _Pragma("unroll") \
  for (int _i = 0; _i < 4; ++_i) { \
    acc[_i][0] = MFMA_BF16_16x16x32(Ab[_i], asb(wreg[0][2*(g)]), acc[_i][0]); \
    acc[_i][1] = MFMA_BF16_16x16x32(Ab[_i], asb(wreg[1][2*(g)]), acc[_i][1]); \
  } \
  _Pragma("unroll") \
  for (int _i = 0; _i < 4; ++_i) { \
    acc[_i][0] = MFMA_BF16_16x16x32(Ab[4+_i], asb(wreg[0][2*(g)+1]), acc[_i][0]); \
    acc[_i][1] = MFMA_BF16_16x16x32(Ab[4+_i], asb(wreg[1][2*(g)+1]), acc[_i][1]); \
  } \
} while (0)

__device__ inline bf16x8 cvt8(float4 a, float4 b) {
  union { bf16x8 v; __hip_bfloat16 h[8]; } u;
  u.h[0] = __float2bfloat16(a.x); u.h[1] = __float2bfloat16(a.y);
  u.h[2] = __float2bfloat16(a.z); u.h[3] = __float2bfloat16(a.w);
  u.h[4] = __float2bfloat16(b.x); u.h[5] = __float2bfloat16(b.y);
  u.h[6] = __float2bfloat16(b.z); u.h[7] = __float2bfloat16(b.w);
  return u.v;
}

// ---------------------------------------------------------------------------
// fp32 -> bf16 quantize (RNE), 8 elems/thread.
// ---------------------------------------------------------------------------
__global__ __launch_bounds__(256) void f32_to_bf16(
    const float* __restrict__ in, __hip_bfloat16* __restrict__ out, long n)
{
  long i = ((long)blockIdx.x * 256 + threadIdx.x) * 8;
  if (i + 8 <= n) {
    float4 a = *(const float4*)(in + i);
    float4 b = *(const float4*)(in + i + 4);
    *(bf16x8*)(out + i) = cvt8(a, b);
  }
}

// ---------------------------------------------------------------------------
// Kernel 1: XH = X @ Wxh^T + bxh  (fp32 in, bf16 out). 128x128 tile, BK=64.
// (unchanged, known-good)
// ---------------------------------------------------------------------------
__global__ __launch_bounds__(256) void xh_gemm(
    const float* __restrict__ X,
    const float* __restrict__ W,
    const float* __restrict__ bias,
    __hip_bfloat16* __restrict__ XH)
{
  const int K = DIN;
  const int N = DH;
  __shared__ __hip_bfloat16 As[128][64];
  __shared__ __hip_bfloat16 Bs[128][64];

  const int nb  = N / 128;
  const int bm  = blockIdx.x / nb;
  const int bn  = blockIdx.x % nb;
  const int m0  = bm * 128, n0 = bn * 128;
  const int tid = threadIdx.x;
  const int lane = tid & 63;
  const int wave = tid >> 6;
  const int wm  = (wave >> 1) * 64;
  const int wn  = (wave & 1) * 64;
  const int col = lane & 15;
  const int quad = lane >> 4;

  const floatx4 Z = {0.f, 0.f, 0.f, 0.f};
  floatx4 acc[4][4];
  #pragma unroll
  for (int i = 0; i < 4; ++i)
    #pragma unroll
    for (int j = 0; j < 4; ++j) acc[i][j] = Z;

  const int srow = tid >> 3;
  const int scol = (tid & 7) * 8;

  for (int k0 = 0; k0 < K; k0 += 64) {
    __syncthreads();
    #pragma unroll
    for (int p = 0; p < 4; ++p) {
      int r = srow + p * 32;
      const float* xs = &X[(long)(m0 + r) * K + k0 + scol];
      const float* wsrc = &W[(long)(n0 + r) * K + k0 + scol];
      *(bf16x8*)(&As[r][scol]) = cvt8(*(const float4*)xs,   *(const float4*)(xs + 4));
      *(bf16x8*)(&Bs[r][scol]) = cvt8(*(const float4*)wsrc, *(const float4*)(wsrc + 4));
    }
    __syncthreads();
    #pragma unroll
    for (int kk = 0; kk < 64; kk += 32) {
      const int kr = kk + quad * 8;
      bf16x8 a[4], b[4];
      #pragma unroll
      for (int i = 0; i < 4; ++i) a[i] = *(const bf16x8*)(&As[wm + i*16 + col][kr]);
      #pragma unroll
      for (int j = 0; j < 4; ++j) b[j] = *(const bf16x8*)(&Bs[wn + j*16 + col][kr]);
      #pragma unroll
      for (int i = 0; i < 4; ++i)
        #pragma unroll
        for (int j = 0; j < 4; ++j)
          acc[i][j] = MFMA_BF16_16x16x32(a[i], b[j], acc[i][j]);
    }
  }

  #pragma unroll
  for (int j = 0; j < 4; ++j) {
    const int n = n0 + wn + j*16 + col;
    const float bv = bias[n];
    #pragma unroll
    for (int i = 0; i < 4; ++i) {
      const int mr = m0 + wm + i*16 + quad*4;
      #pragma unroll
      for (int r = 0; r < 4; ++r)
        XH[(long)(mr + r) * N + n] = __float2bfloat16(acc[i][j][r] + bv);
    }
  }
}

// ---------------------------------------------------------------------------
// Kernel 2: persistent Elman recurrence + final projection.
//   R5's VERIFIED structure (counted 2-buffer pipeline, 64 A-regs in flight,
//   tag-in-sign-bit protocol, 2 intra-block barriers) + ONE change:
//   a 1-dword-per-producer freshness PROBE issued at the end of the previous
//   step. The step's batch loads are issued only after the probe confirms
//   the producers' h_t is visible, so the expensive per-group retries of R5
//   (4 serial RTs/step) collapse to probe re-polls (1 dword RT each).
//   ACQUIRE stays as a rare-straggler backstop (probe samples 1 of each
//   producer's 512 stores).
//   Register discipline (R6 lesson): in-flight asm destinations stay at
//   R5's 64 A-regs + 1 probe dword -- no spill risk under (512,2) bounds.
// ---------------------------------------------------------------------------
__global__ __launch_bounds__(NTHR, 2) void elman_persistent(
    const __hip_bfloat16* __restrict__ XH,    // [64][512][2048] bf16
    const __hip_bfloat16* __restrict__ Whh,   // [2048][2048] bf16
    const __hip_bfloat16* __restrict__ Why,   // [1024][2048] bf16
    const float* __restrict__ bhy,            // [1024] fp32
    __hip_bfloat16* __restrict__ hbuf,        // [2][64][2048] bf16 (buf0=0x00, buf1=0x80)
    float* __restrict__ Y)                    // [64][1024] fp32 = d_out
{
  __shared__ __align__(16) float partial[NW][B_SZ][COLS + 4];  // [8][64][36]
  const int tid  = threadIdx.x;
  const int lane = tid & 63;
  const int wave = tid >> 6;        // 0..7
  const int bid  = blockIdx.x;
  const int n0   = bid * COLS;
  const int col  = lane & 15;
  const int quad = lane >> 4;
  const int kw   = wave * KW;       // this wave's K base

  const int mrow = tid >> 3;        // reduce/store: batch row (0..63)
  const int grp  = tid & 7;         // 8 col-groups of 4
  const int mcol = grp * 4;

  // Probe target: row 0, first dword of producer (8*wave + lane&7)'s slice.
  // All 64 lanes participate (lanes 8.. duplicate lanes 0..7's producers).
  const size_t pelem = (size_t)32 * (8 * wave + (lane & 7));

  // Pin Whh B-frags (asm anti-remat). 2 n-frags x 8 k16 x 16B = 64 VGPR.
  floatx4 wreg[2][8];
  #pragma unroll
  for (int nf = 0; nf < 2; ++nf) {
    const __hip_bfloat16* wrow = Whh + (long)(n0 + nf*16 + col) * DH + kw + quad * 8;
    #pragma unroll
    for (int k16 = 0; k16 < 8; ++k16) {
      wreg[nf][k16] = *(const floatx4*)(wrow + k16 * 32);
      asm volatile("" : "+v"(wreg[nf][k16]));
    }
  }

  // h_0 = +0.0 (tag 0) from host memset of buf0; buf1 pre-filled with 0x80
  // bytes = stale-tag pattern, so step-1 consumers can't pass on init data.

  const __hip_bfloat16* xptr = XH + (size_t)mrow * T_SZ * DH + n0 + mcol;
  const size_t roff = (size_t)kw + (size_t)quad * 8 + (size_t)col * DH;

  // Prologue: probe h_0 (buf0, trivially fresh) + xh_0 prefetch.
  unsigned pv;
  bf16x4 xv, xvn;
  LD32_COH(pv, (const unsigned*)(hbuf + pelem));
  LD64_PLAIN(xvn, xptr);

  const floatx4 Z = {0.f, 0.f, 0.f, 0.f};

  for (int t = 0; t < T_SZ; ++t) {
    const unsigned mexp = ((t >> 1) & 1) ? 0x80008000u : 0u;           // tag of h_t
    const unsigned long long smask =
        (((t + 1) >> 1) & 1) ? 0x8000800080008000ull : 0ull;           // tag of h_{t+1}

    // Everything issued at the previous step's tail (h-store, probe, xh)
    // retires here -- their RTs overlapped the barrier.
    WAIT_VM("0");
    xv = xvn;

    const __hip_bfloat16* hb = hbuf + (size_t)(t & 1) * HELEMS + roff;
    const unsigned* pp = (const unsigned*)(hbuf + (size_t)(t & 1) * HELEMS + pelem);

    // Freshness spin: re-poll is 1 dword RT (not an 8KB batch retry).
    while (!__all(((pv ^ mexp) & 0x80008000u) == 0u)) {
      __builtin_amdgcn_s_sleep(1);
      LD32_COH(pv, pp);
      WAIT_VM("0");
    }

    // Batch through the R5 counted 2-buffer pipeline (fresh with high prob).
    // Audit: issue G0(8)+G1(8)=16 -> WAIT(8) retires G0; MFMA G0; issue G2
    // -> WAIT(8) retires G1; MFMA G1; issue G3 -> WAIT(8) retires G2; ...
    floatx4 acc[4][2];
    #pragma unroll
    for (int i = 0; i < 4; ++i) { acc[i][0] = Z; acc[i][1] = Z; }

    bf16x8 A0[8], A1[8];
    ISSUE_GROUP(A0, 0, hb);
    ISSUE_GROUP(A1, 1, hb);
    WAIT_VM("8");
    ACQUIRE(A0, 0, mexp, hb);
    if (mexp) clean_grp(A0);
    MFMA_GROUP(A0, 0);
    ISSUE_GROUP(A0, 2, hb);
    WAIT_VM("8");
    ACQUIRE(A1, 1, mexp, hb);
    if (mexp) clean_grp(A1);
    MFMA_GROUP(A1, 1);
    ISSUE_GROUP(A1, 3, hb);
    WAIT_VM("8");
    ACQUIRE(A0, 2, mexp, hb);
    if (mexp) clean_grp(A0);
    MFMA_GROUP(A0, 2);
    WAIT_VM("0");
    ACQUIRE(A1, 3, mexp, hb);
    if (mexp) clean_grp(A1);
    MFMA_GROUP(A1, 3);

    // partials to LDS (C/D: m = i*16+quad*4+r, n = nf*16+col)
    #pragma unroll
    for (int i = 0; i < 4; ++i)
      #pragma unroll
      for (int nf = 0; nf < 2; ++nf)
        #pragma unroll
        for (int r = 0; r < 4; ++r)
          partial[wave][i*16 + quad*4 + r][nf*16 + col] = acc[i][nf][r];
    __syncthreads();   // barrier 1: partial writes -> reduce reads (vmcnt=0 here)

    // reduce 8 waves, + xh_t, relu, tag signs, write-through u64 store
    {
      floatx4 s = Z;
      #pragma unroll
      for (int w = 0; w < NW; ++w)
        s += *(const floatx4*)(&partial[w][mrow][mcol]);
      union { bf16x4 v; __hip_bfloat16 hh[4]; unsigned long long q; } o, xu;
      xu.v = xv;
      #pragma unroll
      for (int c = 0; c < 4; ++c) {
        float v = s[c] + __bfloat162float(xu.hh[c]);
        v = v > 0.f ? v : 0.f;
        o.hh[c] = __float2bfloat16(v);
      }
      o.q |= smask;   // stamp step tag into sign bits (values >= 0)
      st_coh64((unsigned long long*)(hbuf + (size_t)((t + 1) & 1) * HELEMS
                                     + (size_t)mrow * DH + n0 + mcol), o.q);
    }

    // Tail: issue next step's probe + xh prefetch; their RTs (and the
    // h-store ack) ride across barrier 2.
    LD32_COH(pv, (const unsigned*)(hbuf + (size_t)((t + 1) & 1) * HELEMS + pelem));
    {
      const int xi = (t + 1 < T_SZ) ? t + 1 : T_SZ - 1;
      LD64_PLAIN(xvn, xptr + (size_t)xi * DH);
    }

    // barrier 2 (raw, NO vmcnt drain): step-t reduce reads complete before
    // any wave's step-t+1 partial writes; store+probe+xh stay in flight.
    asm volatile("s_waitcnt lgkmcnt(0)" ::: "memory");
    __builtin_amdgcn_s_barrier();
    __builtin_amdgcn_sched_barrier(0);
  }

  // Final projection: y = h_final @ Why^T + bhy  (blocks 0..31, fp32 out).
  // h_512 is in buf0, tag (512>>1)&1 = 0. Probe for it was issued at t=511.
  if (n0 < DOUT) {
    WAIT_VM("0");
    const unsigned* pp = (const unsigned*)(hbuf + pelem);
    while (!__all((pv & 0x80008000u) == 0u)) {
      __builtin_amdgcn_s_sleep(1);
      LD32_COH(pv, pp);
      WAIT_VM("0");
    }
    const __hip_bfloat16* hb = hbuf + roff;   // buf0
    floatx4 acc[4][2];
    #pragma unroll
    for (int i = 0; i < 4; ++i) { acc[i][0] = Z; acc[i][1] = Z; }
    bf16x8 A0[8];
    #pragma unroll
    for (int g = 0; g < 4; ++g) {
      ISSUE_GROUP(A0, g, hb);
      WAIT_VM("0");
      ACQUIRE(A0, g, 0u, hb);
      #pragma unroll
      for (int kk = 0; kk < 2; ++kk) {
        const int k16 = 2*g + kk;
        bf16x8 b0 = *(const bf16x8*)(Why + (long)(n0 +      col) * DH + kw + k16*32 + quad*8);
        bf16x8 b1 = *(const bf16x8*)(Why + (long)(n0 + 16 + col) * DH + kw + k16*32 + quad*8);
        #pragma unroll
        for (int i = 0; i < 4; ++i) {
          acc[i][0] = MFMA_BF16_16x16x32(A0[4*kk + i], b0, acc[i][0]);
          acc[i][1] = MFMA_BF16_16x16x32(A0[4*kk + i], b1, acc[i][1]);
        }
      }
    }
    #pragma unroll
    for (int i = 0; i < 4; ++i)
      #pragma unroll
      for (int nf = 0; nf < 2; ++nf)
        #pragma unroll
        for (int r = 0; r < 4; ++r)
          partial[wave][i*16 + quad*4 + r][nf*16 + col] = acc[i][nf][r];
    __syncthreads();
    {
      floatx4 s = Z;
      #pragma unroll
      for (int w = 0; w < NW; ++w)
        s += *(const floatx4*)(&partial[w][mrow][mcol]);
      float4 bv = *(const float4*)(&bhy[n0 + mcol]);
      float4 out;
      out.x = s[0] + bv.x; out.y = s[1] + bv.y;
      out.z = s[2] + bv.z; out.w = s[3] + bv.w;
      *(float4*)(&Y[(size_t)mrow * DOUT + n0 + mcol]) = out;
    }
  }
}

// ---------------------------------------------------------------------------
extern "C" void kernel_launch(void* const* d_in, const int* in_sizes, int n_in,
                              void* d_out, int out_size, void* d_ws, size_t ws_size,
                              hipStream_t stream) {
  const float* x   = (const float*)d_in[0];
  const float* Wxh = (const float*)d_in[1];
  const float* bxh = (const float*)d_in[2];
  const float* Whh = (const float*)d_in[3];
  const float* Why = (const float*)d_in[4];
  const float* bhy = (const float*)d_in[5];
  float* y = (float*)d_out;

  char* ws = (char*)d_ws;
  const size_t XH_BYTES  = (size_t)B_SZ * T_SZ * DH * 2;   // 128 MiB
  const size_t WHH_BYTES = (size_t)DH * DH * 2;            // 8 MiB
  const size_t WHY_BYTES = (size_t)DOUT * DH * 2;          // 4 MiB
  const size_t HB        = (size_t)HELEMS * 2;             // 256 KiB per buffer
  __hip_bfloat16* XH     = (__hip_bfloat16*)ws;
  __hip_bfloat16* Whh_bf = (__hip_bfloat16*)(ws + XH_BYTES);
  __hip_bfloat16* Why_bf = (__hip_bfloat16*)(ws + XH_BYTES + WHH_BYTES);
  __hip_bfloat16* hbuf   = (__hip_bfloat16*)(ws + XH_BYTES + WHH_BYTES + WHY_BYTES);

  hipMemsetAsync(hbuf, 0x00, HB, stream);                  // buf0 = h_0 = +0, tag 0
  hipMemsetAsync((char*)hbuf + HB, 0x80, HB, stream);      // buf1 = stale-tag pattern
  f32_to_bf16<<<dim3((DH*DH)/(256*8)),   dim3(256), 0, stream>>>(Whh, Whh_bf, (long)DH*DH);
  f32_to_bf16<<<dim3((DOUT*DH)/(256*8)), dim3(256), 0, stream>>>(Why, Why_bf, (long)DOUT*DH);
  xh_gemm<<<dim3((32768/128) * (DH/128)), dim3(256), 0, stream>>>(x, Wxh, bxh, XH);
  elman_persistent<<<dim3(NBLK), dim3(NTHR), 0, stream>>>(
      XH, Whh_bf, Why_bf, bhy, hbuf, y);
}

// Round 8
// 2880.329 us; speedup vs baseline: 2.1654x; 1.8275x over previous
//
#include <hip/hip_runtime.h>
#include <hip/hip_bf16.h>

typedef __attribute__((ext_vector_type(8))) short bf16x8;   // 8 bf16 MFMA A/B frag
typedef __attribute__((ext_vector_type(4))) short bf16x4;   // 4 bf16 (8B)
typedef __attribute__((ext_vector_type(4))) float floatx4;  // MFMA C/D frag / 16B container

#define MFMA_BF16_16x16x32(a, b, c) __builtin_amdgcn_mfma_f32_16x16x32_bf16((a), (b), (c), 0, 0, 0)

#define B_SZ 64
#define T_SZ 512
#define DIN  1024
#define DH   2048
#define DOUT 1024
#define NBLK 64          // persistent grid
#define NTHR 512         // 8 waves/block -> 2 waves/SIMD
#define NW   8
#define KW   (DH / NW)   // 256 K-range per wave
#define COLS 32          // h columns owned per block
#define HELEMS ((size_t)B_SZ * DH)   // bf16 elems per h buffer

// h tile layout: [DH/16 = 128 tiles][64 m][16 k] bf16. Element (m, k) lives at
//   (k>>4)*1024 + m*16 + (k&15).
// A-frag (16B/lane) is contiguous; a wave's frag load touches 8 FULLY-USED
// 128B lines (vs 64 sector-used lines in m-major) -> 8x fewer MALL
// transactions on the h exchange, which R2/R5/R7's invariance identified as
// the step-time floor.

union f4b8 { floatx4 f; bf16x8 b; };
__device__ inline bf16x8 asb(floatx4 f) { f4b8 u; u.f = f; return u.b; }
union b8u4 { bf16x8 b; unsigned d[4]; };

__device__ inline void st_coh64(unsigned long long* p, unsigned long long v) {
  __hip_atomic_store(p, v, __ATOMIC_RELAXED, __HIP_MEMORY_SCOPE_AGENT);
}

// MALL-direct coherent loads (bypass L1+L2): no cache-wide fences needed.
#define LD128_COH(dst, ptr) \
  asm volatile("global_load_dwordx4 %0, %1, off sc0 sc1" : "=v"(dst) : "v"(ptr))
#define LD32_COH(dst, ptr) \
  asm volatile("global_load_dword %0, %1, off sc0 sc1" : "=v"(dst) : "v"(ptr))
// plain cached load (read-only XH stream), asm so vmcnt accounting is exact
#define LD64_PLAIN(dst, ptr) \
  asm volatile("global_load_dwordx2 %0, %1, off" : "=v"(dst) : "v"(ptr))
// Counted wait + scheduler fence (rule #18: keep reg-only verify/MFMA below).
#define WAIT_VM(n) do { \
  asm volatile("s_waitcnt vmcnt(" n ")" ::: "memory"); \
  __builtin_amdgcn_sched_barrier(0); } while (0)

// Issue the 8 A-frag loads for k16 = 2g, 2g+1 from per-thread base hb.
// hb already includes (kw>>4 + (quad>>1))*1024 + col*16 + (quad&1)*8.
// k16 step = 2 tiles = 2048 elems; i step = 256 elems (16 m rows).
#define ISSUE_GROUP(Ab, g, hb) do { \
  const __hip_bfloat16* _p0 = (hb) + (size_t)(g) * 4096; \
  const __hip_bfloat16* _p1 = _p0 + 2048; \
  LD128_COH(Ab[0], _p0); \
  LD128_COH(Ab[1], _p0 + 256); \
  LD128_COH(Ab[2], _p0 + 512); \
  LD128_COH(Ab[3], _p0 + 768); \
  LD128_COH(Ab[4], _p1); \
  LD128_COH(Ab[5], _p1 + 256); \
  LD128_COH(Ab[6], _p1 + 512); \
  LD128_COH(Ab[7], _p1 + 768); \
} while (0)

// Tag verify: sign bits of all 32 dwords must equal mexp (0 or 0x80008000).
__device__ inline unsigned grp_mismatch(const bf16x8* Ab, unsigned mexp) {
  unsigned acc = 0u;
  #pragma unroll
  for (int j = 0; j < 8; ++j) {
    b8u4 u; u.b = Ab[j];
    acc |= (u.d[0] ^ mexp) | (u.d[1] ^ mexp) | (u.d[2] ^ mexp) | (u.d[3] ^ mexp);
  }
  return acc & 0x80008000u;
}
// Backstop retry (probe confirmed freshness of one store; catches sibling
// stores that lag). Each retry = one RT, s_sleep-paced.
#define ACQUIRE(Ab, g, mexp, hb) \
  while (!__all(grp_mismatch((Ab), (mexp)) == 0u)) { \
    __builtin_amdgcn_s_sleep(1); \
    ISSUE_GROUP(Ab, g, hb); WAIT_VM("0"); }

__device__ inline void clean_grp(bf16x8* Ab) {   // strip tag-1 sign bits
  #pragma unroll
  for (int j = 0; j < 8; ++j) {
    b8u4 u; u.b = Ab[j];
    u.d[0] &= 0x7fff7fffu; u.d[1] &= 0x7fff7fffu;
    u.d[2] &= 0x7fff7fffu; u.d[3] &= 0x7fff7fffu;
    Ab[j] = u.b;
  }
}

// 16 MFMAs consuming group g (k16 = 2g, 2g+1).
#define MFMA_GROUP(Ab, g) do { \
  _Pragma("unroll") \
  for (int _i = 0; _i < 4; ++_i) { \
    acc[_i][0] = MFMA_BF16_16x16x32(Ab[_i], asb(wreg[0][2*(g)]), acc[_i][0]); \
    acc[_i][1] = MFMA_BF16_16x16x32(Ab[_i], asb(wreg[1][2*(g)]), acc[_i][1]); \
  } \
  _Pragma("unroll") \
  for (int _i = 0; _i < 4; ++_i) { \
    acc[_i][0] = MFMA_BF16_16x16x32(Ab[4+_i], asb(wreg[0][2*(g)+1]), acc[_i][0]); \
    acc[_i][1] = MFMA_BF16_16x16x32(Ab[4+_i], asb(wreg[1][2*(g)+1]), acc[_i][1]); \
  } \
} while (0)

__device__ inline bf16x8 cvt8(float4 a, float4 b) {
  union { bf16x8 v; __hip_bfloat16 h[8]; } u;
  u.h[0] = __float2bfloat16(a.x); u.h[1] = __float2bfloat16(a.y);
  u.h[2] = __float2bfloat16(a.z); u.h[3] = __float2bfloat16(a.w);
  u.h[4] = __float2bfloat16(b.x); u.h[5] = __float2bfloat16(b.y);
  u.h[6] = __float2bfloat16(b.z); u.h[7] = __float2bfloat16(b.w);
  return u.v;
}

// ---------------------------------------------------------------------------
// fp32 -> bf16 quantize (RNE), 8 elems/thread.
// ---------------------------------------------------------------------------
__global__ __launch_bounds__(256) void f32_to_bf16(
    const float* __restrict__ in, __hip_bfloat16* __restrict__ out, long n)
{
  long i = ((long)blockIdx.x * 256 + threadIdx.x) * 8;
  if (i + 8 <= n) {
    float4 a = *(const float4*)(in + i);
    float4 b = *(const float4*)(in + i + 4);
    *(bf16x8*)(out + i) = cvt8(a, b);
  }
}

// ---------------------------------------------------------------------------
// Kernel 1: XH = X @ Wxh^T + bxh  (fp32 in, bf16 out). 128x128 tile, BK=64.
// (unchanged, known-good)
// ---------------------------------------------------------------------------
__global__ __launch_bounds__(256) void xh_gemm(
    const float* __restrict__ X,
    const float* __restrict__ W,
    const float* __restrict__ bias,
    __hip_bfloat16* __restrict__ XH)
{
  const int K = DIN;
  const int N = DH;
  __shared__ __hip_bfloat16 As[128][64];
  __shared__ __hip_bfloat16 Bs[128][64];

  const int nb  = N / 128;
  const int bm  = blockIdx.x / nb;
  const int bn  = blockIdx.x % nb;
  const int m0  = bm * 128, n0 = bn * 128;
  const int tid = threadIdx.x;
  const int lane = tid & 63;
  const int wave = tid >> 6;
  const int wm  = (wave >> 1) * 64;
  const int wn  = (wave & 1) * 64;
  const int col = lane & 15;
  const int quad = lane >> 4;

  const floatx4 Z = {0.f, 0.f, 0.f, 0.f};
  floatx4 acc[4][4];
  #pragma unroll
  for (int i = 0; i < 4; ++i)
    #pragma unroll
    for (int j = 0; j < 4; ++j) acc[i][j] = Z;

  const int srow = tid >> 3;
  const int scol = (tid & 7) * 8;

  for (int k0 = 0; k0 < K; k0 += 64) {
    __syncthreads();
    #pragma unroll
    for (int p = 0; p < 4; ++p) {
      int r = srow + p * 32;
      const float* xs = &X[(long)(m0 + r) * K + k0 + scol];
      const float* wsrc = &W[(long)(n0 + r) * K + k0 + scol];
      *(bf16x8*)(&As[r][scol]) = cvt8(*(const float4*)xs,   *(const float4*)(xs + 4));
      *(bf16x8*)(&Bs[r][scol]) = cvt8(*(const float4*)wsrc, *(const float4*)(wsrc + 4));
    }
    __syncthreads();
    #pragma unroll
    for (int kk = 0; kk < 64; kk += 32) {
      const int kr = kk + quad * 8;
      bf16x8 a[4], b[4];
      #pragma unroll
      for (int i = 0; i < 4; ++i) a[i] = *(const bf16x8*)(&As[wm + i*16 + col][kr]);
      #pragma unroll
      for (int j = 0; j < 4; ++j) b[j] = *(const bf16x8*)(&Bs[wn + j*16 + col][kr]);
      #pragma unroll
      for (int i = 0; i < 4; ++i)
        #pragma unroll
        for (int j = 0; j < 4; ++j)
          acc[i][j] = MFMA_BF16_16x16x32(a[i], b[j], acc[i][j]);
    }
  }

  #pragma unroll
  for (int j = 0; j < 4; ++j) {
    const int n = n0 + wn + j*16 + col;
    const float bv = bias[n];
    #pragma unroll
    for (int i = 0; i < 4; ++i) {
      const int mr = m0 + wm + i*16 + quad*4;
      #pragma unroll
      for (int r = 0; r < 4; ++r)
        XH[(long)(mr + r) * N + n] = __float2bfloat16(acc[i][j][r] + bv);
    }
  }
}

// ---------------------------------------------------------------------------
// Kernel 2: persistent Elman recurrence + final projection.
//   R7 structure (tag-in-sign-bit dataflow, probe, counted 2-buffer pipeline,
//   2 intra-block barriers, 64 in-flight A-regs) with ONE change: h stored in
//   MFMA-tile layout [128][64m][16k] so every A-frag wave-load touches 8
//   fully-used lines instead of 64 sector-used lines (8x fewer coherent MALL
//   transactions -- the common floor of R2/R5/R7).
// ---------------------------------------------------------------------------
__global__ __launch_bounds__(NTHR, 2) void elman_persistent(
    const __hip_bfloat16* __restrict__ XH,    // [64][512][2048] bf16
    const __hip_bfloat16* __restrict__ Whh,   // [2048][2048] bf16
    const __hip_bfloat16* __restrict__ Why,   // [1024][2048] bf16
    const float* __restrict__ bhy,            // [1024] fp32
    __hip_bfloat16* __restrict__ hbuf,        // [2][128][64][16] bf16 (buf0=0x00, buf1=0x80)
    float* __restrict__ Y)                    // [64][1024] fp32 = d_out
{
  __shared__ __align__(16) float partial[NW][B_SZ][COLS + 4];  // [8][64][36]
  const int tid  = threadIdx.x;
  const int lane = tid & 63;
  const int wave = tid >> 6;        // 0..7
  const int bid  = blockIdx.x;
  const int n0   = bid * COLS;
  const int col  = lane & 15;
  const int quad = lane >> 4;
  const int kw   = wave * KW;       // this wave's K base

  const int mrow = tid >> 3;        // reduce/store: batch row (0..63)
  const int grp  = tid & 7;         // 8 col-groups of 4
  const int mcol = grp * 4;

  // Probe: first dword of producer (8*wave + lane&7)'s tile range
  // (covers cols p*32, p*32+1 at m=0 -- written by that block's thread 0).
  const size_t pelem = (size_t)(8 * wave + (lane & 7)) * 2048;

  // h-store address (tile layout): cols c0 = n0+mcol (4 contiguous k in one
  // tile), row mrow -> elems ((c0>>4)*1024 + mrow*16 + (c0&15)), 8B store.
  const size_t soff = (size_t)((n0 + mcol) >> 4) * 1024 + (size_t)mrow * 16
                    + (size_t)((n0 + mcol) & 15);

  // Per-thread A-frag read base within a buffer.
  const size_t roff = (size_t)((kw >> 4) + (quad >> 1)) * 1024
                    + (size_t)col * 16 + (size_t)(quad & 1) * 8;

  // Pin Whh B-frags (asm anti-remat). 2 n-frags x 8 k16 x 16B = 64 VGPR.
  floatx4 wreg[2][8];
  #pragma unroll
  for (int nf = 0; nf < 2; ++nf) {
    const __hip_bfloat16* wrow = Whh + (long)(n0 + nf*16 + col) * DH + kw + quad * 8;
    #pragma unroll
    for (int k16 = 0; k16 < 8; ++k16) {
      wreg[nf][k16] = *(const floatx4*)(wrow + k16 * 32);
      asm volatile("" : "+v"(wreg[nf][k16]));
    }
  }

  // h_0 = +0.0 (tag 0) from host memset of buf0; buf1 pre-filled with 0x80
  // bytes = stale-tag pattern (per-element, layout-independent).

  const __hip_bfloat16* xptr = XH + (size_t)mrow * T_SZ * DH + n0 + mcol;

  // Prologue: probe h_0 (buf0, trivially fresh) + xh_0 prefetch.
  unsigned pv;
  bf16x4 xv, xvn;
  LD32_COH(pv, (const unsigned*)(hbuf + pelem));
  LD64_PLAIN(xvn, xptr);

  const floatx4 Z = {0.f, 0.f, 0.f, 0.f};

  for (int t = 0; t < T_SZ; ++t) {
    const unsigned mexp = ((t >> 1) & 1) ? 0x80008000u : 0u;           // tag of h_t
    const unsigned long long smask =
        (((t + 1) >> 1) & 1) ? 0x8000800080008000ull : 0ull;           // tag of h_{t+1}

    // Tail-issued ops (h-store, probe, xh) retire here; RTs overlapped bar 2.
    WAIT_VM("0");
    xv = xvn;

    const __hip_bfloat16* hb = hbuf + (size_t)(t & 1) * HELEMS + roff;
    const unsigned* pp = (const unsigned*)(hbuf + (size_t)(t & 1) * HELEMS + pelem);

    // Freshness spin: re-poll is 1 dword RT (not an 8KB batch retry).
    while (!__all(((pv ^ mexp) & 0x80008000u) == 0u)) {
      __builtin_amdgcn_s_sleep(1);
      LD32_COH(pv, pp);
      WAIT_VM("0");
    }

    // Counted 2-buffer pipeline (R5-verified): 64 A-regs in flight max.
    floatx4 acc[4][2];
    #pragma unroll
    for (int i = 0; i < 4; ++i) { acc[i][0] = Z; acc[i][1] = Z; }

    bf16x8 A0[8], A1[8];
    ISSUE_GROUP(A0, 0, hb);
    ISSUE_GROUP(A1, 1, hb);
    WAIT_VM("8");
    ACQUIRE(A0, 0, mexp, hb);
    if (mexp) clean_grp(A0);
    MFMA_GROUP(A0, 0);
    ISSUE_GROUP(A0, 2, hb);
    WAIT_VM("8");
    ACQUIRE(A1, 1, mexp, hb);
    if (mexp) clean_grp(A1);
    MFMA_GROUP(A1, 1);
    ISSUE_GROUP(A1, 3, hb);
    WAIT_VM("8");
    ACQUIRE(A0, 2, mexp, hb);
    if (mexp) clean_grp(A0);
    MFMA_GROUP(A0, 2);
    WAIT_VM("0");
    ACQUIRE(A1, 3, mexp, hb);
    if (mexp) clean_grp(A1);
    MFMA_GROUP(A1, 3);

    // partials to LDS (C/D: m = i*16+quad*4+r, n = nf*16+col)
    #pragma unroll
    for (int i = 0; i < 4; ++i)
      #pragma unroll
      for (int nf = 0; nf < 2; ++nf)
        #pragma unroll
        for (int r = 0; r < 4; ++r)
          partial[wave][i*16 + quad*4 + r][nf*16 + col] = acc[i][nf][r];
    __syncthreads();   // barrier 1: partial writes -> reduce reads (vmcnt=0 here)

    // reduce 8 waves, + xh_t, relu, tag signs, write-through u64 store
    {
      floatx4 s = Z;
      #pragma unroll
      for (int w = 0; w < NW; ++w)
        s += *(const floatx4*)(&partial[w][mrow][mcol]);
      union { bf16x4 v; __hip_bfloat16 hh[4]; unsigned long long q; } o, xu;
      xu.v = xv;
      #pragma unroll
      for (int c = 0; c < 4; ++c) {
        float v = s[c] + __bfloat162float(xu.hh[c]);
        v = v > 0.f ? v : 0.f;
        o.hh[c] = __float2bfloat16(v);
      }
      o.q |= smask;   // stamp step tag into sign bits (values >= 0)
      st_coh64((unsigned long long*)(hbuf + (size_t)((t + 1) & 1) * HELEMS + soff),
               o.q);
    }

    // Tail: next step's probe + xh prefetch ride across barrier 2 with the
    // h-store ack.
    LD32_COH(pv, (const unsigned*)(hbuf + (size_t)((t + 1) & 1) * HELEMS + pelem));
    {
      const int xi = (t + 1 < T_SZ) ? t + 1 : T_SZ - 1;
      LD64_PLAIN(xvn, xptr + (size_t)xi * DH);
    }

    // barrier 2 (raw, NO vmcnt drain): step-t reduce reads complete before
    // any wave's step-t+1 partial writes; store+probe+xh stay in flight.
    asm volatile("s_waitcnt lgkmcnt(0)" ::: "memory");
    __builtin_amdgcn_s_barrier();
    __builtin_amdgcn_sched_barrier(0);
  }

  // Final projection: y = h_final @ Why^T + bhy  (blocks 0..31, fp32 out).
  // h_512 is in buf0, tag (512>>1)&1 = 0. Probe for it was issued at t=511.
  if (n0 < DOUT) {
    WAIT_VM("0");
    const unsigned* pp = (const unsigned*)(hbuf + pelem);
    while (!__all((pv & 0x80008000u) == 0u)) {
      __builtin_amdgcn_s_sleep(1);
      LD32_COH(pv, pp);
      WAIT_VM("0");
    }
    const __hip_bfloat16* hb = hbuf + roff;   // buf0
    floatx4 acc[4][2];
    #pragma unroll
    for (int i = 0; i < 4; ++i) { acc[i][0] = Z; acc[i][1] = Z; }
    bf16x8 A0[8];
    #pragma unroll
    for (int g = 0; g < 4; ++g) {
      ISSUE_GROUP(A0, g, hb);
      WAIT_VM("0");
      ACQUIRE(A0, g, 0u, hb);
      #pragma unroll
      for (int kk = 0; kk < 2; ++kk) {
        const int k16 = 2*g + kk;
        bf16x8 b0 = *(const bf16x8*)(Why + (long)(n0 +      col) * DH + kw + k16*32 + quad*8);
        bf16x8 b1 = *(const bf16x8*)(Why + (long)(n0 + 16 + col) * DH + kw + k16*32 + quad*8);
        #pragma unroll
        for (int i = 0; i < 4; ++i) {
          acc[i][0] = MFMA_BF16_16x16x32(A0[4*kk + i], b0, acc[i][0]);
          acc[i][1] = MFMA_BF16_16x16x32(A0[4*kk + i], b1, acc[i][1]);
        }
      }
    }
    #pragma unroll
    for (int i = 0; i < 4; ++i)
      #pragma unroll
      for (int nf = 0; nf < 2; ++nf)
        #pragma unroll
        for (int r = 0; r < 4; ++r)
          partial[wave][i*16 + quad*4 + r][nf*16 + col] = acc[i][nf][r];
    __syncthreads();
    {
      floatx4 s = Z;
      #pragma unroll
      for (int w = 0; w < NW; ++w)
        s += *(const floatx4*)(&partial[w][mrow][mcol]);
      float4 bv = *(const float4*)(&bhy[n0 + mcol]);
      float4 out;
      out.x = s[0] + bv.x; out.y = s[1] + bv.y;
      out.z = s[2] + bv.z; out.w = s[3] + bv.w;
      *(float4*)(&Y[(size_t)mrow * DOUT + n0 + mcol]) = out;
    }
  }
}

// ---------------------------------------------------------------------------
extern "C" void kernel_launch(void* const* d_in, const int* in_sizes, int n_in,
                              void* d_out, int out_size, void* d_ws, size_t ws_size,
                              hipStream_t stream) {
  const float* x   = (const float*)d_in[0];
  const float* Wxh = (const float*)d_in[1];
  const float* bxh = (const float*)d_in[2];
  const float* Whh = (const float*)d_in[3];
  const float* Why = (const float*)d_in[4];
  const float* bhy = (const float*)d_in[5];
  float* y = (float*)d_out;

  char* ws = (char*)d_ws;
  const size_t XH_BYTES  = (size_t)B_SZ * T_SZ * DH * 2;   // 128 MiB
  const size_t WHH_BYTES = (size_t)DH * DH * 2;            // 8 MiB
  const size_t WHY_BYTES = (size_t)DOUT * DH * 2;          // 4 MiB
  const size_t HB        = (size_t)HELEMS * 2;             // 256 KiB per buffer
  __hip_bfloat16* XH     = (__hip_bfloat16*)ws;
  __hip_bfloat16* Whh_bf = (__hip_bfloat16*)(ws + XH_BYTES);
  __hip_bfloat16* Why_bf = (__hip_bfloat16*)(ws + XH_BYTES + WHH_BYTES);
  __hip_bfloat16* hbuf   = (__hip_bfloat16*)(ws + XH_BYTES + WHH_BYTES + WHY_BYTES);

  hipMemsetAsync(hbuf, 0x00, HB, stream);                  // buf0 = h_0 = +0, tag 0
  hipMemsetAsync((char*)hbuf + HB, 0x80, HB, stream);      // buf1 = stale-tag pattern
  f32_to_bf16<<<dim3((DH*DH)/(256*8)),   dim3(256), 0, stream>>>(Whh, Whh_bf, (long)DH*DH);
  f32_to_bf16<<<dim3((DOUT*DH)/(256*8)), dim3(256), 0, stream>>>(Why, Why_bf, (long)DOUT*DH);
  xh_gemm<<<dim3((32768/128) * (DH/128)), dim3(256), 0, stream>>>(x, Wxh, bxh, XH);
  elman_persistent<<<dim3(NBLK), dim3(NTHR), 0, stream>>>(
      XH, Whh_bf, Why_bf, bhy, hbuf, y);
}